// Round 2
// baseline (95.638 us; speedup 1.0000x reference)
//
#include <hip/hip_runtime.h>

// HalutMatmul forward on MI355X.
// Per row n: h[c][p] = sum_d I[n, c*9+d] * A[c][d][p]   (c=0..15, p=0..3)
//            code_c  = 4-level tree descent: bit_l = (h[c][l] > T[c*15 + node_l])
//            out[n][m] = sum_c L[m][c][code_c]
// S and B from the reference are structural and baked into the control flow.
//
// Round-2 changes vs round-1 (55.4 us):
//  - L table in LDS as bf16 pairs, transposed to [c][k][m] with 16B-chunk XOR
//    swizzle -> 128 ds_read_b128/row instead of 1024 ds_read_b32, 32 KiB LDS.
//  - Output transposed through LDS (reusing the table region after a barrier)
//    and stored as wave-contiguous float4 -> kills the 4.2x write inflation.
//  - f64 hash/tree decisions unchanged (exact codes, absmax was 0.0).

#define NROWS (1024 * 128)

__global__ __launch_bounds__(256) void halut_fwd(
    const float* __restrict__ I,
    const float* __restrict__ A,
    const float* __restrict__ T,
    const float* __restrict__ L,
    float* __restrict__ out)
{
    // 32 KiB: bf16-pair LUT [col=c*16+k][32 dwords], chunk-swizzled.
    // Reused as float[128][64] output staging after the gather phase.
    __shared__ uint32_t sTab[8192];
    __shared__ double   sA[576];   // A promoted to f64: [c][d][p]
    __shared__ double   sT[240];   // thresholds, f64

    const int tid = threadIdx.x;

    // ---- stage L: thread t owns column col = c*16+k = t ----
    {
        const int k  = tid & 15;
        const int sw = k & 7;
        uint32_t* colp = sTab + (tid << 5);
        #pragma unroll
        for (int p = 0; p < 32; ++p) {
            // m = 2p, 2p+1 ; global idx = m*256 + col  (lane-contiguous: coalesced)
            const uint32_t ua = __float_as_uint(L[(2 * p) * 256 + tid]);
            const uint32_t ub = __float_as_uint(L[(2 * p + 1) * 256 + tid]);
            // RTNE f32 -> bf16
            const uint32_t ba = (ua + 0x7fffu + ((ua >> 16) & 1u)) >> 16;
            const uint32_t bb = (ub + 0x7fffu + ((ub >> 16) & 1u)) >> 16;
            const int phys = ((((p >> 2) ^ sw) << 2) | (p & 3));
            colp[phys] = (bb << 16) | ba;   // lo half = m=2p, hi half = m=2p+1
        }
    }
    for (int i = tid; i < 576; i += 256) sA[i] = (double)A[i];
    if (tid < 240) sT[tid] = (double)T[tid];
    __syncthreads();

    const int    row = blockIdx.x * 256 + tid;
    const float* rp  = I + (size_t)row * 144;

    float acc[64];
    #pragma unroll
    for (int m = 0; m < 64; ++m) acc[m] = 0.0f;

    #pragma unroll
    for (int g = 0; g < 4; ++g) {            // 4 codebooks per group, 36 floats
        float4 buf[9];
        const float4* rv = (const float4*)(rp + g * 36);  // 144B-aligned
        #pragma unroll
        for (int i = 0; i < 9; ++i) buf[i] = rv[i];
        const float* bf = (const float*)buf;

        #pragma unroll
        for (int cc = 0; cc < 4; ++cc) {
            const int c = g * 4 + cc;
            double h0 = 0.0, h1 = 0.0, h2 = 0.0, h3 = 0.0;
            #pragma unroll
            for (int d = 0; d < 9; ++d) {
                const double  x  = (double)bf[cc * 9 + d];
                const double* ap = &sA[(c * 9 + d) * 4];
                h0 = fma(x, ap[0], h0);
                h1 = fma(x, ap[1], h1);
                h2 = fma(x, ap[2], h2);
                h3 = fma(x, ap[3], h3);
            }
            const double* tp = &sT[c * 15];
            int p;
            p =         (h0 > tp[0]);
            p = 2 * p + (h1 > tp[1 + p]);
            p = 2 * p + (h2 > tp[3 + p]);
            p = 2 * p + (h3 > tp[7 + p]);

            // gather-accumulate: column (c,p), 8 swizzled 16B chunks = 64 m
            const uint32_t* col = sTab + (((c << 4) + p) << 5);
            const int sw = (p & 7) << 2;
            #pragma unroll
            for (int j = 0; j < 8; ++j) {
                const uint4 w = *(const uint4*)(col + ((j << 2) ^ sw));
                const int mb = j << 3;
                acc[mb + 0] += __uint_as_float(w.x << 16);
                acc[mb + 1] += __uint_as_float(w.x & 0xffff0000u);
                acc[mb + 2] += __uint_as_float(w.y << 16);
                acc[mb + 3] += __uint_as_float(w.y & 0xffff0000u);
                acc[mb + 4] += __uint_as_float(w.z << 16);
                acc[mb + 5] += __uint_as_float(w.z & 0xffff0000u);
                acc[mb + 6] += __uint_as_float(w.w << 16);
                acc[mb + 7] += __uint_as_float(w.w & 0xffff0000u);
            }
        }
    }

    // ---- coalesced write-out: transpose 128 rows at a time through sTab ----
    __syncthreads();                     // everyone done reading the LUT
    float* sO = (float*)sTab;            // 128 rows x 64 floats = 32 KiB

    #pragma unroll
    for (int half = 0; half < 2; ++half) {
        if ((tid >> 7) == half) {
            const int r = tid & 127;
            #pragma unroll
            for (int mc = 0; mc < 16; ++mc) {
                float4 v = make_float4(acc[4*mc], acc[4*mc+1], acc[4*mc+2], acc[4*mc+3]);
                *(float4*)&sO[(r << 6) + ((mc ^ (r & 15)) << 2)] = v;
            }
        }
        __syncthreads();
        const size_t rowbase = (size_t)blockIdx.x * 256 + half * 128;
        float4* op = (float4*)(out + rowbase * 64);
        #pragma unroll
        for (int q = 0; q < 8; ++q) {
            const int f  = tid + (q << 8);        // 0..2047 float4s
            const int r2 = f >> 4;
            const int m2 = f & 15;
            op[f] = *(const float4*)&sO[(r2 << 6) + ((m2 ^ (r2 & 15)) << 2)];
        }
        __syncthreads();                 // protect sO before next half writes
    }
}

extern "C" void kernel_launch(void* const* d_in, const int* in_sizes, int n_in,
                              void* d_out, int out_size, void* d_ws, size_t ws_size,
                              hipStream_t stream) {
    const float* I = (const float*)d_in[0];
    const float* A = (const float*)d_in[1];
    const float* T = (const float*)d_in[2];
    const float* L = (const float*)d_in[3];
    float* outp = (float*)d_out;

    const int nblocks = NROWS / 256;   // 512 blocks x 256 threads, 1 row/thread
    halut_fwd<<<nblocks, 256, 0, stream>>>(I, A, T, L, outp);
}

// Round 3
// 29.869 us; speedup vs baseline: 3.2018x; 3.2018x over previous
//
#include <hip/hip_runtime.h>

// HalutMatmul forward on MI355X.
// Per row n: h[c][p] = sum_d I[n, c*9+d] * A[c][d][p]   (c=0..15, p=0..3)
//            code_c  = 4-level tree descent: bit_l = (h[c][l] > T[c*15 + node_l])
//            out[n][m] = sum_c L[m][c][code_c]
// S and B from the reference are structural and baked into the control flow.
//
// Round-3: round-1 gather structure (f32 LUT, 136 VGPR, absmax 0.0) +
//  - LUT as float2 pairs over m: 512 ds_read_b64/row instead of 1024 b32.
//  - Single-pass non-divergent output transpose reusing the 64 KB LUT LDS:
//    dump acc -> barrier -> contiguous float4 stores (fixes the 4x write
//    inflation without round-2's divergent epilogue that spilled at 256 VGPR).

#define NROWS (1024 * 128)

__global__ __launch_bounds__(256) void halut_fwd(
    const float* __restrict__ I,
    const float* __restrict__ A,
    const float* __restrict__ T,
    const float* __restrict__ L,
    float* __restrict__ out)
{
    // 64 KiB: LUT as float2 [m2=m/2][col=c*16+k]  (gather phase)
    //         then reused as float[256][64] output staging (epilogue).
    __shared__ float  sBuf[16384];
    __shared__ double sA[576];   // A promoted to f64: [c][d][p]
    __shared__ double sT[240];   // thresholds, f64

    const int tid = threadIdx.x;

    {   // ---- stage L: thread t owns column col = t; coalesced across lanes ----
        float2* sL2 = (float2*)sBuf;
        #pragma unroll
        for (int p2 = 0; p2 < 32; ++p2) {
            const float a = L[(2 * p2)     * 256 + tid];
            const float b = L[(2 * p2 + 1) * 256 + tid];
            sL2[p2 * 256 + tid] = make_float2(a, b);
        }
    }
    for (int i = tid; i < 576; i += 256) sA[i] = (double)A[i];
    if (tid < 240) sT[tid] = (double)T[tid];
    __syncthreads();

    const int    row = blockIdx.x * 256 + tid;
    const float* rp  = I + (size_t)row * 144;

    float acc[64];
    #pragma unroll
    for (int m = 0; m < 64; ++m) acc[m] = 0.0f;

    #pragma unroll
    for (int g = 0; g < 4; ++g) {            // 4 codebooks per group, 36 floats
        float4 buf[9];
        const float4* rv = (const float4*)(rp + g * 36);  // 144B-aligned
        #pragma unroll
        for (int i = 0; i < 9; ++i) buf[i] = rv[i];
        const float* bf = (const float*)buf;

        #pragma unroll
        for (int cc = 0; cc < 4; ++cc) {
            const int c = g * 4 + cc;
            // per-codebook soft hash in f64 (decision-boundary exactness)
            double h0 = 0.0, h1 = 0.0, h2 = 0.0, h3 = 0.0;
            #pragma unroll
            for (int d = 0; d < 9; ++d) {
                const double  x  = (double)bf[cc * 9 + d];
                const double* ap = &sA[(c * 9 + d) * 4];
                h0 = fma(x, ap[0], h0);
                h1 = fma(x, ap[1], h1);
                h2 = fma(x, ap[2], h2);
                h3 = fma(x, ap[3], h3);
            }
            // tree descent; node_l = (2^l - 1) + prefix
            const double* tp = &sT[c * 15];
            int p;
            p =         (h0 > tp[0]);
            p = 2 * p + (h1 > tp[1 + p]);
            p = 2 * p + (h2 > tp[3 + p]);
            p = 2 * p + (h3 > tp[7 + p]);

            // gather-accumulate column (c,p): 32 ds_read_b64, conflict-free
            // (16 p-slots x 2 words cover all 32 banks; same-p lanes broadcast)
            const float2* colp = (const float2*)sBuf + (c * 16 + p);
            #pragma unroll
            for (int p2 = 0; p2 < 32; ++p2) {
                const float2 v = colp[p2 * 256];
                acc[2 * p2]     += v.x;
                acc[2 * p2 + 1] += v.y;
            }
        }
    }

    // ---- single-pass output transpose through sBuf (LUT is dead now) ----
    __syncthreads();                 // all gather reads done
    float* sO = sBuf;                // [256 rows][64 m], 16B-chunk XOR swizzle
    #pragma unroll
    for (int mc = 0; mc < 16; ++mc) {
        *(float4*)&sO[(tid << 6) + ((mc ^ (tid & 15)) << 2)] =
            make_float4(acc[4*mc], acc[4*mc+1], acc[4*mc+2], acc[4*mc+3]);
    }
    __syncthreads();

    float4* op = (float4*)(out + (size_t)blockIdx.x * (256 * 64));
    #pragma unroll
    for (int j = 0; j < 16; ++j) {   // 4096 float4 = 64 KB, fully contiguous
        const int F  = tid + (j << 8);
        const int r2 = F >> 4;
        const int m2 = F & 15;
        op[F] = *(const float4*)&sO[(r2 << 6) + ((m2 ^ (r2 & 15)) << 2)];
    }
}

extern "C" void kernel_launch(void* const* d_in, const int* in_sizes, int n_in,
                              void* d_out, int out_size, void* d_ws, size_t ws_size,
                              hipStream_t stream) {
    const float* I = (const float*)d_in[0];
    const float* A = (const float*)d_in[1];
    const float* T = (const float*)d_in[2];
    const float* L = (const float*)d_in[3];
    float* outp = (float*)d_out;

    const int nblocks = NROWS / 256;   // 512 blocks x 256 threads, 1 row/thread
    halut_fwd<<<nblocks, 256, 0, stream>>>(I, A, T, L, outp);
}